// Round 3
// baseline (772.945 us; speedup 1.0000x reference)
//
#include <hip/hip_runtime.h>
#include <math.h>

typedef _Float16 f16;
typedef _Float16 f16x8 __attribute__((ext_vector_type(8)));
typedef float f32x4 __attribute__((ext_vector_type(4)));

#define NN 5000
#define NE 160000

// ---------------- ws layout (bytes, all 16B-aligned) ----------------
#define OFF_W2T   0ul          // f16 [21][256][4][8] fragment-linear (344064 B)
#define OFF_W3T   344064ul     // f16 [1248]      (6 taps * 208, c>=200 zero)
#define OFF_WT1   346560ul     // f16 [512][96]
#define OFF_WT2   444864ul     // f16 [512][128]
#define OFF_WT3   575936ul
#define OFF_WT4   707008ul
#define OFF_WT5   838080ul
#define OFF_WT6   969152ul     // f16 [64][128] (rows>=32 zero)
#define OFF_H0    985536ul     // f16 [5000][96] (cols 94,95 zero)
#define OFF_HA    1945536ul    // f16 [5000][128]
#define OFF_HB    3225536ul    // f16 [5000][128]
#define OFF_C     4505536ul    // f32 [5000][512]; ALSO W1T lives here before first gemm
#define OFF_DEG   14745536ul   // int [5000]
#define OFF_IP    14765536ul   // int [5001]
#define OFF_CUR   14785568ul   // int [5000]
#define OFF_DINV  14805568ul   // f32 [5000]
#define OFF_CSRS  14825568ul   // int [160000]
#define OFF_CSRN  15465568ul   // f32 [160000]
// W1T f16 [112][32] aliases OFF_C (dead before first gemm writes C)
#define OFF_W1T   OFF_C

// ---------------- CNN LDS layout (dynamic, 71168 B) ----------------
// phase 0/1: s_in | A1[208][40] | C1: 208 rows x 256B (XOR-swizzled)
// phase 2+ : C2[147][216] aliases A1/C1 region
#define L_IN   0
#define L_BUF  1280
#define L_A1   (L_BUF)
#define L_C1   (L_BUF + 16640)            // 17920
#define L_C2   (L_BUF)
#define LDS_TOTAL (17920 + 208*256)       // 71168

// ==================== prep kernels ====================
// W2T fragment-linear: idx = ((kc*256 + n)*4 + g)*8 + j  <->  k = kc*32+g*8+j
__global__ void prep_w2t(const float* __restrict__ w, f16* __restrict__ W2T) {
  int i = blockIdx.x*256 + threadIdx.x;
  if (i >= 21*256*32) return;
  int j = i & 7, g = (i >> 3) & 3, n = (i >> 5) & 255, kc = i >> 13;
  int k = kc*32 + g*8 + j;
  int tap = k / 112, c = k - tap*112;
  float v = 0.f;
  if (n < 200 && c < 100 && tap < 6) v = w[n*600 + c*6 + tap];  // e2_w[n][c][ky][kx]
  W2T[i] = (f16)v;
}

__global__ void prep_w3t(const float* __restrict__ w, f16* __restrict__ W3T) {
  int i = blockIdx.x*256 + threadIdx.x;
  if (i >= 1248) return;
  int tap = i / 208, c = i - tap*208;
  float v = (c < 200) ? w[c*6 + tap] : 0.f;           // e3_w[0][c][ky][kx]
  W3T[i] = (f16)v;
}

__global__ void prep_w1t(const float* __restrict__ w, f16* __restrict__ W1T) {
  int i = blockIdx.x*256 + threadIdx.x;
  if (i >= 112*32) return;
  int n = i >> 5, k = i & 31;
  float v = (n < 100 && k < 9) ? w[n*9 + k] : 0.f;    // e1_w[n][0][ky][kx], k=ky*3+kx
  W1T[i] = (f16)v;
}

__global__ void prep_wt(const float* __restrict__ wi, const float* __restrict__ wr,
                        f16* __restrict__ WT, int Kst, int Fin, int Fout, int Kpad, int R) {
  int i = blockIdx.x*256 + threadIdx.x;
  if (i >= R*Kpad) return;
  int n = i / Kpad, kk = i - n*Kpad;
  float v = 0.f;
  if (kk < Fin) {
    int path = n / (Kst*Fout);
    if (path < 2) {
      int rem = n - path*(Kst*Fout);
      int k = rem / Fout, fo = rem - k*Fout;
      const float* w = (path == 0) ? wi : wr;
      v = w[(k*Fin + kk)*Fout + fo];                  // a_w[k][kk][fo]
    }
  }
  WT[i] = (f16)v;
}

// ==================== graph kernels ====================
__global__ void zero_kernel(int* __restrict__ deg, int* __restrict__ cur) {
  int i = blockIdx.x*256 + threadIdx.x;
  if (i < NN) { deg[i] = 0; cur[i] = 0; }
}

__global__ void deg_kernel(const int* __restrict__ ei, int* __restrict__ deg) {
  int e = blockIdx.x*256 + threadIdx.x;
  if (e < NE) atomicAdd(&deg[ei[NE + e]], 1);
}

__global__ __launch_bounds__(1024) void scan_kernel(const int* __restrict__ deg,
                                                    int* __restrict__ ip,
                                                    float* __restrict__ dinv) {
  __shared__ int buf[1024];
  __shared__ int s_carry;
  const int tid = threadIdx.x;
  if (tid == 0) s_carry = 0;
  __syncthreads();
  for (int base = 0; base < NN; base += 1024) {
    int i = base + tid;
    int v = (i < NN) ? deg[i] : 0;
    buf[tid] = v;
    __syncthreads();
    for (int off = 1; off < 1024; off <<= 1) {
      int t = (tid >= off) ? buf[tid - off] : 0;
      __syncthreads();
      buf[tid] += t;
      __syncthreads();
    }
    int incl = buf[tid];
    int c = s_carry;
    if (i < NN) {
      ip[i] = c + incl - v;                 // exclusive scan
      dinv[i] = (v > 0) ? rsqrtf((float)v) : 0.f;
    }
    __syncthreads();
    if (tid == 1023) s_carry = c + buf[1023];
    __syncthreads();
  }
  if (tid == 0) ip[NN] = s_carry;
}

__global__ void csr_fill(const int* __restrict__ ei, const float* __restrict__ dinv,
                         const int* __restrict__ ip, int* __restrict__ cur,
                         int* __restrict__ csrs, float* __restrict__ csrn) {
  int e = blockIdx.x*256 + threadIdx.x;
  if (e >= NE) return;
  int s = ei[e], d = ei[NE + e];
  int pos = ip[d] + atomicAdd(&cur[d], 1);
  csrs[pos] = s;
  csrn[pos] = dinv[s]*dinv[d];
}

// ==================== fused CNN encoder ====================
// one block per node; conv1/conv2/conv3 all MFMA; LDS phases aliased -> 2 blocks/CU
__global__ __launch_bounds__(512, 2) void cnn_kernel(
    const float* __restrict__ inp, const f16* __restrict__ W1T, const float* __restrict__ b1,
    const f16* __restrict__ W2T, const float* __restrict__ b2,
    const f16* __restrict__ W3T, const float* __restrict__ b3,
    f16* __restrict__ h0)
{
  extern __shared__ char smem[];
  float* s_in = (float*)(smem + L_IN);    // [53][6] f32
  f16*   s_a1 = (f16*)(smem + L_A1);      // [208][40] im2col for conv1 (k<9 data)
  char*  c1b  = smem + L_C1;              // 208 rows x 256B, XOR-swizzled f16 [row][cin]
  f16*   s_c2 = (f16*)(smem + L_C2);      // [147][216] row=y2*3+x2, col=cout (200..207 zero)

  const int node = blockIdx.x;
  const int tid  = threadIdx.x;
  const int lane = tid & 63, wid = tid >> 6;
  const int l15 = lane & 15, g = lane >> 4;

  for (int i = tid; i < 318; i += 512) s_in[i] = inp[node*318 + i];
  __syncthreads();

  // ---- build conv1 im2col A: A1[m][k] = in[(y+ky)*6 + x+kx], m=y*4+x, k=ky*3+kx ----
  for (int i = tid; i < 208*32; i += 512) {
    int m = i >> 5, k = i & 31;
    float v = 0.f;
    if (m < 204 && k < 9) {
      int y = m >> 2, x = m & 3;
      int ky = (k >= 6) ? 2 : (k >= 3 ? 1 : 0);
      int kx = k - ky*3;
      v = s_in[(y + ky)*6 + x + kx];
    }
    s_a1[m*40 + k] = (f16)v;
  }
  __syncthreads();

  // ---- conv1 (1->100, 3x3) as MFMA: M=204(pad208) N=100(pad112) K=9(pad32) ----
  for (int p = wid; p < 91; p += 8) {
    int mt = p % 13, nt = p / 13;
    f16x8 a = *(const f16x8*)(s_a1 + (mt*16 + l15)*40 + g*8);
    f16x8 b = *(const f16x8*)(W1T + (nt*16 + l15)*32 + g*8);
    f32x4 acc = (f32x4){0.f,0.f,0.f,0.f};
    acc = __builtin_amdgcn_mfma_f32_16x16x32_f16(a, b, acc, 0, 0, 0);
    int c = nt*16 + l15;
    float bias = (c < 100) ? b1[c] : 0.f;
    #pragma unroll
    for (int j = 0; j < 4; j++) {
      int m = mt*16 + g*4 + j;
      float v = acc[j] + bias;
      v = v > 0.f ? v : 0.01f*v;
      *(f16*)(c1b + (m << 8) + (((c << 1) ^ ((m & 7) << 4)))) = (f16)v;
    }
  }
  __syncthreads();

  // ---- conv2 (100->200, 3x2) as MFMA GEMM: M=147(pad160) N=200(pad256) K=6taps*112 ----
  const int wm = wid >> 2, wn = wid & 3;          // 2x4 wave grid, wave tile 80x64

  int rbase[5];
  #pragma unroll
  for (int mi = 0; mi < 5; mi++) {
    int p = (wm*5 + mi)*16 + l15;
    int pp = p < 147 ? p : 0;
    int y2 = pp / 3;
    rbase[mi] = y2*4 + (pp - y2*3);               // row in s_c1 for tap (0,0)
  }

  f32x4 acc[5][4];
  #pragma unroll
  for (int mi = 0; mi < 5; mi++)
    #pragma unroll
    for (int ni = 0; ni < 4; ni++)
      acc[mi][ni] = (f32x4){0.f,0.f,0.f,0.f};

  const int lofs = l15*32 + g*8;                  // fragment-linear lane offset
  const f16* bbase = W2T + wn*2048 + lofs;
  #pragma unroll
  for (int kc = 0; kc < 21; kc++) {
    int k = kc*32 + g*8;
    int tap = k / 112;
    int c = k - tap*112;
    int dr = ((tap >> 1) << 2) + (tap & 1);       // ky*4+kx
    f16x8 a[5], b[4];
    #pragma unroll
    for (int mi = 0; mi < 5; mi++) {
      int row = rbase[mi] + dr;
      a[mi] = *(const f16x8*)(c1b + (row << 8) + (((c << 1) ^ ((row & 7) << 4))));
    }
    const f16* bkc = bbase + kc*8192;
    #pragma unroll
    for (int ni = 0; ni < 4; ni++)
      b[ni] = *(const f16x8*)(bkc + ni*512);
    #pragma unroll
    for (int mi = 0; mi < 5; mi++)
      #pragma unroll
      for (int ni = 0; ni < 4; ni++)
        acc[mi][ni] = __builtin_amdgcn_mfma_f32_16x16x32_f16(a[mi], b[ni], acc[mi][ni], 0, 0, 0);
  }

  __syncthreads();   // all waves done READING s_c1/s_a1 before s_c2 overwrites them

  // epilogue: +bias, leaky, store f16 channels-last (cols 200..207 exact zeros)
  #pragma unroll
  for (int ni = 0; ni < 4; ni++) {
    int n = wn*64 + ni*16 + l15;
    if (n < 208) {
      float bias = (n < 200) ? b2[n] : 0.f;
      #pragma unroll
      for (int mi = 0; mi < 5; mi++) {
        #pragma unroll
        for (int j = 0; j < 4; j++) {
          int m = (wm*5 + mi)*16 + g*4 + j;
          if (m < 147) {
            float v = acc[mi][ni][j] + bias;
            v = v > 0.f ? v : 0.01f*v;
            s_c2[m*216 + n] = (f16)v;
          }
        }
      }
    }
  }
  __syncthreads();

  // ---- conv3 (200->1, 3x2) as skinny MFMA + tanh -> h0 ----
  if (wid < 6) {
    int p = wid*16 + l15;
    int q = p < 94 ? p : 0;
    int y3 = q >> 1, x3 = q & 1;
    int r3 = y3*3 + x3;
    f16 bmask = (l15 == 0) ? (f16)1.f : (f16)0.f;
    f32x4 acc3 = (f32x4){0.f,0.f,0.f,0.f};
    #pragma unroll
    for (int kc = 0; kc < 39; kc++) {
      int k = kc*32 + g*8;
      int tap = k / 208;
      int c = k - tap*208;
      int dr = (tap >> 1)*3 + (tap & 1);          // ky*3+kx
      f16x8 a = *(const f16x8*)(s_c2 + (r3 + dr)*216 + c);
      f16x8 b = *(const f16x8*)(W3T + k);
      #pragma unroll
      for (int j = 0; j < 8; j++) b[j] *= bmask;  // only col 0 of B is real
      acc3 = __builtin_amdgcn_mfma_f32_16x16x32_f16(a, b, acc3, 0, 0, 0);
    }
    if (l15 == 0) {
      float bb = b3[0];
      #pragma unroll
      for (int j = 0; j < 4; j++) {
        int qq = wid*16 + g*4 + j;
        float v = (qq < 94) ? tanhf(acc3[j] + bb) : 0.f;
        h0[node*96 + qq] = (f16)v;
      }
    }
  }
}

// ==================== generic MFMA GEMM: C[M][N] = A[M][K(f16)] * B[N][K(f16)]^T ====================
template<int K>
__global__ __launch_bounds__(256, 4) void gemm_kernel(
    const f16* __restrict__ A, const f16* __restrict__ B, float* __restrict__ C,
    int M, int N)
{
  constexpr int LK = K + 8;                      // +8 f16 pad: conflict-free frag reads
  __shared__ f16 sA[64*LK];
  __shared__ f16 sB[64*LK];
  const int tid = threadIdx.x;
  const int m0 = blockIdx.x*64, n0 = blockIdx.y*64;
  constexpr int SEGS = K/8;
  for (int i = tid; i < 64*SEGS; i += 256) {
    int row = i / SEGS, seg = i - row*SEGS;
    int gm = m0 + row; if (gm >= M) gm = M - 1;
    *(f16x8*)(sA + row*LK + seg*8) = *(const f16x8*)(A + (size_t)gm*K + seg*8);
    *(f16x8*)(sB + row*LK + seg*8) = *(const f16x8*)(B + (size_t)(n0 + row)*K + seg*8);
  }
  __syncthreads();
  const int lane = tid & 63, wid = tid >> 6;
  const int l15 = lane & 15, g = lane >> 4;
  const int wm = wid >> 1, wn = wid & 1;         // 2x2 waves, 32x32 each
  f32x4 acc[2][2];
  #pragma unroll
  for (int mi = 0; mi < 2; mi++)
    #pragma unroll
    for (int ni = 0; ni < 2; ni++)
      acc[mi][ni] = (f32x4){0.f,0.f,0.f,0.f};
  #pragma unroll
  for (int kc = 0; kc < K/32; kc++) {
    f16x8 a[2], b[2];
    #pragma unroll
    for (int mi = 0; mi < 2; mi++)
      a[mi] = *(const f16x8*)(sA + (wm*32 + mi*16 + l15)*LK + kc*32 + g*8);
    #pragma unroll
    for (int ni = 0; ni < 2; ni++)
      b[ni] = *(const f16x8*)(sB + (wn*32 + ni*16 + l15)*LK + kc*32 + g*8);
    #pragma unroll
    for (int mi = 0; mi < 2; mi++)
      #pragma unroll
      for (int ni = 0; ni < 2; ni++)
        acc[mi][ni] = __builtin_amdgcn_mfma_f32_16x16x32_f16(a[mi], b[ni], acc[mi][ni], 0, 0, 0);
  }
  #pragma unroll
  for (int mi = 0; mi < 2; mi++)
    #pragma unroll
    for (int ni = 0; ni < 2; ni++)
      #pragma unroll
      for (int j = 0; j < 4; j++) {
        int m = m0 + wm*32 + mi*16 + g*4 + j;
        int n = n0 + wn*32 + ni*16 + l15;
        if (m < M) C[(size_t)m*N + n] = acc[mi][ni][j];
      }
}

// ==================== ARMA combine kernels ====================
// C layout per row: [t_k0(128) | t_k1(128) | root_k0(128) | root_k1(128)]
__global__ __launch_bounds__(256) void combine128(
    const float* __restrict__ C, const int* __restrict__ ip,
    const int* __restrict__ csrs, const float* __restrict__ csrn,
    const float* __restrict__ bias, f16* __restrict__ hout)
{
  const int d = blockIdx.x*4 + (threadIdx.x >> 6);
  const int lane = threadIdx.x & 63;
  const int i0 = ip[d], i1 = ip[d+1];
  float a00 = 0.f, a01 = 0.f, a10 = 0.f, a11 = 0.f;
  float b00 = 0.f, b01 = 0.f, b10 = 0.f, b11 = 0.f;
  int e = i0;
  for (; e + 1 < i1; e += 2) {                    // 2-edge unroll: 8 independent streams
    int s0 = csrs[e], s1 = csrs[e+1];
    float w0 = csrn[e], w1 = csrn[e+1];
    const float* t0 = C + (size_t)s0*512;
    const float* t1 = C + (size_t)s1*512;
    a00 += w0*t0[lane];       a01 += w0*t0[lane+64];
    a10 += w0*t0[lane+128];   a11 += w0*t0[lane+192];
    b00 += w1*t1[lane];       b01 += w1*t1[lane+64];
    b10 += w1*t1[lane+128];   b11 += w1*t1[lane+192];
  }
  if (e < i1) {
    int s = csrs[e];
    float w = csrn[e];
    const float* t = C + (size_t)s*512;
    a00 += w*t[lane];       a01 += w*t[lane+64];
    a10 += w*t[lane+128];   a11 += w*t[lane+192];
  }
  a00 += b00; a01 += b01; a10 += b10; a11 += b11;
  const float* r = C + (size_t)d*512 + 256;
  float o0 = fmaxf(a00 + r[lane]     + bias[lane],     0.f)
           + fmaxf(a10 + r[lane+128] + bias[lane+128], 0.f);
  float o1 = fmaxf(a01 + r[lane+64]  + bias[lane+64],  0.f)
           + fmaxf(a11 + r[lane+192] + bias[lane+192], 0.f);
  hout[(size_t)d*128 + lane]      = (f16)tanhf(0.5f*o0);
  hout[(size_t)d*128 + lane + 64] = (f16)tanhf(0.5f*o1);
}

// layer 6 (K=1, Fout=16): C row = [t(16) | root(16) | zeros(32)]; relu -> softmax -> out
__global__ __launch_bounds__(256) void combine_out(
    const float* __restrict__ C, const int* __restrict__ ip,
    const int* __restrict__ csrs, const float* __restrict__ csrn,
    const float* __restrict__ bias, float* __restrict__ out)
{
  const int d = blockIdx.x*4 + (threadIdx.x >> 6);
  const int lane = threadIdx.x & 63;
  const int f = lane & 15;
  const int i0 = ip[d], i1 = ip[d+1];
  float a = 0.f, b = 0.f;
  int e = i0;
  for (; e + 1 < i1; e += 2) {
    a += csrn[e]   * C[(size_t)csrs[e]*64 + f];
    b += csrn[e+1] * C[(size_t)csrs[e+1]*64 + f];
  }
  if (e < i1) a += csrn[e] * C[(size_t)csrs[e]*64 + f];
  a += b;
  float v = fmaxf(a + C[(size_t)d*64 + 16 + f] + bias[f], 0.f);
  float m = v;
  #pragma unroll
  for (int off = 1; off < 16; off <<= 1) m = fmaxf(m, __shfl_xor(m, off));
  float ev = expf(v - m);
  float s = ev;
  #pragma unroll
  for (int off = 1; off < 16; off <<= 1) s += __shfl_xor(s, off);
  if (lane < 16) out[(size_t)d*16 + lane] = ev / s;
}

// ==================== host ====================
extern "C" void kernel_launch(void* const* d_in, const int* in_sizes, int n_in,
                              void* d_out, int out_size, void* d_ws, size_t ws_size,
                              hipStream_t stream)
{
  const float* inputs = (const float*)d_in[0];
  const int*   ei     = (const int*)d_in[1];
  const float* e1w = (const float*)d_in[2];
  const float* e1b = (const float*)d_in[3];
  const float* e2w = (const float*)d_in[4];
  const float* e2b = (const float*)d_in[5];
  const float* e3w = (const float*)d_in[6];
  const float* e3b = (const float*)d_in[7];
  const float *awi[6], *awr[6], *ab[6];
  for (int i = 0; i < 6; i++) {
    awi[i] = (const float*)d_in[8 + 3*i];
    awr[i] = (const float*)d_in[9 + 3*i];
    ab[i]  = (const float*)d_in[10 + 3*i];
  }
  char* ws = (char*)d_ws;
  f16* W2T = (f16*)(ws + OFF_W2T);
  f16* W3T = (f16*)(ws + OFF_W3T);
  f16* W1T = (f16*)(ws + OFF_W1T);
  f16* WT[6] = { (f16*)(ws + OFF_WT1), (f16*)(ws + OFF_WT2), (f16*)(ws + OFF_WT3),
                 (f16*)(ws + OFF_WT4), (f16*)(ws + OFF_WT5), (f16*)(ws + OFF_WT6) };
  f16* H0 = (f16*)(ws + OFF_H0);
  f16* HA = (f16*)(ws + OFF_HA);
  f16* HB = (f16*)(ws + OFF_HB);
  float* C = (float*)(ws + OFF_C);
  int* DEG = (int*)(ws + OFF_DEG);
  int* IP  = (int*)(ws + OFF_IP);
  int* CUR = (int*)(ws + OFF_CUR);
  float* DINV = (float*)(ws + OFF_DINV);
  int* CSRS = (int*)(ws + OFF_CSRS);
  float* CSRN = (float*)(ws + OFF_CSRN);

  (void)hipFuncSetAttribute((const void*)cnn_kernel,
                            hipFuncAttributeMaxDynamicSharedMemorySize, LDS_TOTAL);

  // weight prep (W1T aliases C; cnn reads it before first gemm writes C)
  prep_w2t<<<672, 256, 0, stream>>>(e2w, W2T);
  prep_w3t<<<5, 256, 0, stream>>>(e3w, W3T);
  prep_w1t<<<14, 256, 0, stream>>>(e1w, W1T);
  prep_wt<<<192, 256, 0, stream>>>(awi[0], awr[0], WT[0], 2, 94, 128, 96, 512);
  for (int l = 1; l < 5; l++)
    prep_wt<<<256, 256, 0, stream>>>(awi[l], awr[l], WT[l], 2, 128, 128, 128, 512);
  prep_wt<<<32, 256, 0, stream>>>(awi[5], awr[5], WT[5], 1, 128, 16, 128, 64);

  // graph norm + CSR by dst
  zero_kernel<<<20, 256, 0, stream>>>(DEG, CUR);
  deg_kernel<<<625, 256, 0, stream>>>(ei, DEG);
  scan_kernel<<<1, 1024, 0, stream>>>(DEG, IP, DINV);
  csr_fill<<<625, 256, 0, stream>>>(ei, DINV, IP, CUR, CSRS, CSRN);

  // fused CNN encoder -> h0 f16 [5000][96]
  cnn_kernel<<<NN, 512, LDS_TOTAL, stream>>>(inputs, W1T, e1b, W2T, e2b, W3T, e3b, H0);

  // ARMA stack
  gemm_kernel<96><<<dim3(79, 8), 256, 0, stream>>>(H0, WT[0], C, NN, 512);
  combine128<<<1250, 256, 0, stream>>>(C, IP, CSRS, CSRN, ab[0], HA);
  gemm_kernel<128><<<dim3(79, 8), 256, 0, stream>>>(HA, WT[1], C, NN, 512);
  combine128<<<1250, 256, 0, stream>>>(C, IP, CSRS, CSRN, ab[1], HB);
  gemm_kernel<128><<<dim3(79, 8), 256, 0, stream>>>(HB, WT[2], C, NN, 512);
  combine128<<<1250, 256, 0, stream>>>(C, IP, CSRS, CSRN, ab[2], HA);
  gemm_kernel<128><<<dim3(79, 8), 256, 0, stream>>>(HA, WT[3], C, NN, 512);
  combine128<<<1250, 256, 0, stream>>>(C, IP, CSRS, CSRN, ab[3], HB);
  gemm_kernel<128><<<dim3(79, 8), 256, 0, stream>>>(HB, WT[4], C, NN, 512);
  combine128<<<1250, 256, 0, stream>>>(C, IP, CSRS, CSRN, ab[4], HA);
  gemm_kernel<128><<<dim3(79, 1), 256, 0, stream>>>(HA, WT[5], C, NN, 64);
  combine_out<<<1250, 256, 0, stream>>>(C, IP, CSRS, CSRN, ab[5], (float*)d_out);
}

// Round 4
// 683.056 us; speedup vs baseline: 1.1316x; 1.1316x over previous
//
#include <hip/hip_runtime.h>
#include <math.h>

typedef _Float16 f16;
typedef _Float16 f16x8 __attribute__((ext_vector_type(8)));
typedef float f32x4 __attribute__((ext_vector_type(4)));

#define NN 5000
#define NE 160000

// ---------------- ws layout (bytes, all 16B-aligned) ----------------
#define OFF_W2T   0ul          // f16 [21][256][4][8] fragment-linear (344064 B)
#define OFF_W3T   344064ul     // f16 [1248]      (6 taps * 208, c>=200 zero)
#define OFF_WT1   346560ul     // f16 [512][96]
#define OFF_WT2   444864ul     // f16 [512][128]
#define OFF_WT3   575936ul
#define OFF_WT4   707008ul
#define OFF_WT5   838080ul
#define OFF_WT6   969152ul     // f16 [64][128] (rows>=32 zero)
#define OFF_H0    985536ul     // f16 [5000][96] (cols 94,95 zero)
#define OFF_HA    1945536ul    // f16 [5000][128]
#define OFF_HB    3225536ul    // f16 [5000][128]
#define OFF_C     4505536ul    // f32 [5000][512]; ALSO W1T lives here before first gemm
#define OFF_DEG   14745536ul   // int [5000]
#define OFF_IP    14765536ul   // int [5001]
#define OFF_CUR   14785568ul   // int [5000]
#define OFF_DINV  14805568ul   // f32 [5000]
#define OFF_CSRS  14825568ul   // int [160000]
#define OFF_CSRN  15465568ul   // f32 [160000]
// W1T f16 [112][32] aliases OFF_C (dead before first gemm writes C)
#define OFF_W1T   OFF_C

// ---------------- CNN LDS layout (dynamic, 74496 B) ----------------
// phase 0/1: s_in(1280) | A1[208][40](16640) | C1: 208 rows x 136 f16 (56576)
// phase 2+ : C2[147][216] (63504) aliases A1+C1 region (starts at L_BUF)
#define L_IN   0
#define L_BUF  1280
#define L_A1   (L_BUF)
#define L_C1   (L_BUF + 16640)            // 17920
#define L_C2   (L_BUF)
#define C1_STRIDE 136                     // f16 elems; 272 B (== 16 mod 128 -> bank rotate)
#define LDS_TOTAL (17920 + 208*272)       // 74496; x2 = 148992 <= 160 KiB

// ==================== prep kernels ====================
// W2T fragment-linear: idx = ((kc*256 + n)*4 + g)*8 + j  <->  k = kc*32+g*8+j
__global__ void prep_w2t(const float* __restrict__ w, f16* __restrict__ W2T) {
  int i = blockIdx.x*256 + threadIdx.x;
  if (i >= 21*256*32) return;
  int j = i & 7, g = (i >> 3) & 3, n = (i >> 5) & 255, kc = i >> 13;
  int k = kc*32 + g*8 + j;
  int tap = k / 112, c = k - tap*112;
  float v = 0.f;
  if (n < 200 && c < 100 && tap < 6) v = w[n*600 + c*6 + tap];  // e2_w[n][c][ky][kx]
  W2T[i] = (f16)v;
}

__global__ void prep_w3t(const float* __restrict__ w, f16* __restrict__ W3T) {
  int i = blockIdx.x*256 + threadIdx.x;
  if (i >= 1248) return;
  int tap = i / 208, c = i - tap*208;
  float v = (c < 200) ? w[c*6 + tap] : 0.f;           // e3_w[0][c][ky][kx]
  W3T[i] = (f16)v;
}

__global__ void prep_w1t(const float* __restrict__ w, f16* __restrict__ W1T) {
  int i = blockIdx.x*256 + threadIdx.x;
  if (i >= 112*32) return;
  int n = i >> 5, k = i & 31;
  float v = (n < 100 && k < 9) ? w[n*9 + k] : 0.f;    // e1_w[n][0][ky][kx], k=ky*3+kx
  W1T[i] = (f16)v;
}

__global__ void prep_wt(const float* __restrict__ wi, const float* __restrict__ wr,
                        f16* __restrict__ WT, int Kst, int Fin, int Fout, int Kpad, int R) {
  int i = blockIdx.x*256 + threadIdx.x;
  if (i >= R*Kpad) return;
  int n = i / Kpad, kk = i - n*Kpad;
  float v = 0.f;
  if (kk < Fin) {
    int path = n / (Kst*Fout);
    if (path < 2) {
      int rem = n - path*(Kst*Fout);
      int k = rem / Fout, fo = rem - k*Fout;
      const float* w = (path == 0) ? wi : wr;
      v = w[(k*Fin + kk)*Fout + fo];                  // a_w[k][kk][fo]
    }
  }
  WT[i] = (f16)v;
}

// ==================== graph kernels ====================
__global__ void zero_kernel(int* __restrict__ deg, int* __restrict__ cur) {
  int i = blockIdx.x*256 + threadIdx.x;
  if (i < NN) { deg[i] = 0; cur[i] = 0; }
}

__global__ void deg_kernel(const int* __restrict__ ei, int* __restrict__ deg) {
  int e = blockIdx.x*256 + threadIdx.x;
  if (e < NE) atomicAdd(&deg[ei[NE + e]], 1);
}

__global__ __launch_bounds__(1024) void scan_kernel(const int* __restrict__ deg,
                                                    int* __restrict__ ip,
                                                    float* __restrict__ dinv) {
  __shared__ int buf[1024];
  __shared__ int s_carry;
  const int tid = threadIdx.x;
  if (tid == 0) s_carry = 0;
  __syncthreads();
  for (int base = 0; base < NN; base += 1024) {
    int i = base + tid;
    int v = (i < NN) ? deg[i] : 0;
    buf[tid] = v;
    __syncthreads();
    for (int off = 1; off < 1024; off <<= 1) {
      int t = (tid >= off) ? buf[tid - off] : 0;
      __syncthreads();
      buf[tid] += t;
      __syncthreads();
    }
    int incl = buf[tid];
    int c = s_carry;
    if (i < NN) {
      ip[i] = c + incl - v;                 // exclusive scan
      dinv[i] = (v > 0) ? rsqrtf((float)v) : 0.f;
    }
    __syncthreads();
    if (tid == 1023) s_carry = c + buf[1023];
    __syncthreads();
  }
  if (tid == 0) ip[NN] = s_carry;
}

__global__ void csr_fill(const int* __restrict__ ei, const float* __restrict__ dinv,
                         const int* __restrict__ ip, int* __restrict__ cur,
                         int* __restrict__ csrs, float* __restrict__ csrn) {
  int e = blockIdx.x*256 + threadIdx.x;
  if (e >= NE) return;
  int s = ei[e], d = ei[NE + e];
  int pos = ip[d] + atomicAdd(&cur[d], 1);
  csrs[pos] = s;
  csrn[pos] = dinv[s]*dinv[d];
}

// ==================== fused CNN encoder ====================
// one block per node; target: 80 AGPR acc + <=48 arch VGPR -> 2 blocks/CU spill-free
__global__ __launch_bounds__(512, 4) void cnn_kernel(
    const float* __restrict__ inp, const f16* __restrict__ W1T, const float* __restrict__ b1,
    const f16* __restrict__ W2T, const float* __restrict__ b2,
    const f16* __restrict__ W3T, const float* __restrict__ b3,
    f16* __restrict__ h0)
{
  extern __shared__ char smem[];
  float* s_in = (float*)(smem + L_IN);    // [53][6] f32
  f16*   s_a1 = (f16*)(smem + L_A1);      // [208][40] im2col for conv1 (k<9 data)
  f16*   s_c1 = (f16*)(smem + L_C1);      // [208][136] row=y*4+x, col=cin (100..111 zero)
  f16*   s_c2 = (f16*)(smem + L_C2);      // [147][216] row=y2*3+x2, col=cout (200..207 zero)

  const int node = blockIdx.x;
  const int tid  = threadIdx.x;
  const int lane = tid & 63, wid = tid >> 6;
  const int l15 = lane & 15, g = lane >> 4;

  for (int i = tid; i < 318; i += 512) s_in[i] = inp[node*318 + i];
  // zero the cin pad cols 100..111 of c1 (rows 0..207)
  for (int i = tid; i < 208*12; i += 512) {
    int r = i / 12, c = 100 + (i - r*12);
    s_c1[r*C1_STRIDE + c] = (f16)0.f;
  }
  __syncthreads();

  // ---- build conv1 im2col A: A1[m][k] = in[(y+ky)*6 + x+kx], m=y*4+x, k=ky*3+kx ----
  for (int i = tid; i < 208*32; i += 512) {
    int m = i >> 5, k = i & 31;
    float v = 0.f;
    if (m < 204 && k < 9) {
      int y = m >> 2, x = m & 3;
      int ky = (k >= 6) ? 2 : (k >= 3 ? 1 : 0);
      int kx = k - ky*3;
      v = s_in[(y + ky)*6 + x + kx];
    }
    s_a1[m*40 + k] = (f16)v;
  }
  __syncthreads();

  // ---- conv1 (1->100, 3x3) as MFMA: M=204(pad208) N=100(pad112) K=9(pad32) ----
  for (int p = wid; p < 91; p += 8) {
    int mt = p % 13, nt = p / 13;
    f16x8 a = *(const f16x8*)(s_a1 + (mt*16 + l15)*40 + g*8);
    f16x8 b = *(const f16x8*)(W1T + (nt*16 + l15)*32 + g*8);
    f32x4 acc = (f32x4){0.f,0.f,0.f,0.f};
    acc = __builtin_amdgcn_mfma_f32_16x16x32_f16(a, b, acc, 0, 0, 0);
    int c = nt*16 + l15;
    float bias = (c < 100) ? b1[c] : 0.f;
    #pragma unroll
    for (int j = 0; j < 4; j++) {
      int m = mt*16 + g*4 + j;
      float v = acc[j] + bias;
      v = v > 0.f ? v : 0.01f*v;
      s_c1[m*C1_STRIDE + c] = (f16)v;
    }
  }
  __syncthreads();

  // ---- conv2 (100->200, 3x2) as MFMA GEMM: M=147(pad160) N=200(pad256) K=6taps*112 ----
  const int wm = wid >> 2, wn = wid & 3;          // 2x4 wave grid, wave tile 80x64

  // per-mi LDS base pointers (include g*8 so per-kc offset is a compile-time imm)
  const f16* abase[5];
  #pragma unroll
  for (int mi = 0; mi < 5; mi++) {
    int p = (wm*5 + mi)*16 + l15;
    int pp = p < 147 ? p : 0;
    int y2 = pp / 3;
    abase[mi] = s_c1 + (y2*4 + (pp - y2*3))*C1_STRIDE + g*8;
  }

  f32x4 acc[5][4];
  #pragma unroll
  for (int mi = 0; mi < 5; mi++)
    #pragma unroll
    for (int ni = 0; ni < 4; ni++)
      acc[mi][ni] = (f32x4){0.f,0.f,0.f,0.f};

  const f16* bbase = W2T + wn*2048 + l15*32 + g*8;   // fragment-linear
  #pragma unroll
  for (int kc = 0; kc < 21; kc++) {
    int k = kc*32;                                   // g*8 folded into bases
    int tap = (kc*32 + g*0) >= 0 ? (kc*32)/112 : 0;  // tap from kc only when 32|kc*32 spans
    // recompute per-element (g matters for tap boundary): do it exactly:
    f16x8 b[4];
    const f16* bkc = bbase + kc*8192;
    #pragma unroll
    for (int ni = 0; ni < 4; ni++)
      b[ni] = *(const f16x8*)(bkc + ni*512);
    #pragma unroll
    for (int mi = 0; mi < 5; mi++) {
      // exact k for this lane-group: kg = kc*32 + g*8 ; tap/c derived per unrolled kc+g
      // g in {0..3}: kc*32+g*8 spans one tap boundary only if (kc*32)/112 != (kc*32+24)/112
      // handled exactly below via runtime g-dependent terms folded at compile time per kc:
      int kg0 = kc*32;               // lane-group base handled via tap arithmetic:
      int tap0 = kg0 / 112;
      int rem0 = kg0 - tap0*112;     // c for g=0
      // c(g) = rem0 + g*8 - (rem0 + g*8 >= 112 ? 112 : 0); tap(g) likewise +1
      int cross = 0;                 // computed below per g at compile time (kc unrolled)
      (void)cross;
      int cg = rem0;                 // base; add g*8 and wrap
      int tapg = tap0;
      // wrap check (compile-time per kc since rem0 const, g runtime but small):
      // use arithmetic without branch:
      int cfull = cg + g*8;
      int wrap = cfull >= 112 ? 1 : 0;
      int c = cfull - wrap*112;
      tapg = tap0 + wrap;
      int dr = ((tapg >> 1) << 2) + (tapg & 1);     // ky*4+kx
      f16x8 a = *(const f16x8*)(abase[mi] + dr*C1_STRIDE + (c - g*8)); // abase has +g*8
      #pragma unroll
      for (int ni = 0; ni < 4; ni++)
        acc[mi][ni] = __builtin_amdgcn_mfma_f32_16x16x32_f16(a, b[ni], acc[mi][ni], 0, 0, 0);
    }
  }

  __syncthreads();   // all waves done READING s_c1/s_a1 before s_c2 overwrites them

  // epilogue: +bias, leaky, store f16 channels-last (cols 200..207 exact zeros)
  #pragma unroll
  for (int ni = 0; ni < 4; ni++) {
    int n = wn*64 + ni*16 + l15;
    if (n < 208) {
      float bias = (n < 200) ? b2[n] : 0.f;
      #pragma unroll
      for (int mi = 0; mi < 5; mi++) {
        #pragma unroll
        for (int j = 0; j < 4; j++) {
          int m = (wm*5 + mi)*16 + g*4 + j;
          if (m < 147) {
            float v = acc[mi][ni][j] + bias;
            v = v > 0.f ? v : 0.01f*v;
            s_c2[m*216 + n] = (f16)v;
          }
        }
      }
    }
  }
  __syncthreads();

  // ---- conv3 (200->1, 3x2) as skinny MFMA + tanh -> h0 ----
  if (wid < 6) {
    int p = wid*16 + l15;
    int q = p < 94 ? p : 0;
    int y3 = q >> 1, x3 = q & 1;
    int r3 = y3*3 + x3;
    f16 bmask = (l15 == 0) ? (f16)1.f : (f16)0.f;
    f32x4 acc3 = (f32x4){0.f,0.f,0.f,0.f};
    #pragma unroll
    for (int kc = 0; kc < 39; kc++) {
      int k = kc*32 + g*8;
      int tap = k / 208;
      int c = k - tap*208;
      int dr = (tap >> 1)*3 + (tap & 1);          // ky*3+kx
      f16x8 a = *(const f16x8*)(s_c2 + (r3 + dr)*216 + c);
      f16x8 b = *(const f16x8*)(W3T + k);
      #pragma unroll
      for (int j = 0; j < 8; j++) b[j] *= bmask;  // only col 0 of B is real
      acc3 = __builtin_amdgcn_mfma_f32_16x16x32_f16(a, b, acc3, 0, 0, 0);
    }
    if (l15 == 0) {
      float bb = b3[0];
      #pragma unroll
      for (int j = 0; j < 4; j++) {
        int qq = wid*16 + g*4 + j;
        float v = (qq < 94) ? tanhf(acc3[j] + bb) : 0.f;
        h0[node*96 + qq] = (f16)v;
      }
    }
  }
}

// ==================== generic MFMA GEMM: C[M][N] = A[M][K(f16)] * B[N][K(f16)]^T ====================
template<int K>
__global__ __launch_bounds__(256, 4) void gemm_kernel(
    const f16* __restrict__ A, const f16* __restrict__ B, float* __restrict__ C,
    int M, int N)
{
  constexpr int LK = K + 8;                      // +8 f16 pad: conflict-free frag reads
  __shared__ f16 sA[64*LK];
  __shared__ f16 sB[64*LK];
  const int tid = threadIdx.x;
  const int m0 = blockIdx.x*64, n0 = blockIdx.y*64;
  constexpr int SEGS = K/8;
  for (int i = tid; i < 64*SEGS; i += 256) {
    int row = i / SEGS, seg = i - row*SEGS;
    int gm = m0 + row; if (gm >= M) gm = M - 1;
    *(f16x8*)(sA + row*LK + seg*8) = *(const f16x8*)(A + (size_t)gm*K + seg*8);
    *(f16x8*)(sB + row*LK + seg*8) = *(const f16x8*)(B + (size_t)(n0 + row)*K + seg*8);
  }
  __syncthreads();
  const int lane = tid & 63, wid = tid >> 6;
  const int l15 = lane & 15, g = lane >> 4;
  const int wm = wid >> 1, wn = wid & 1;         // 2x2 waves, 32x32 each
  f32x4 acc[2][2];
  #pragma unroll
  for (int mi = 0; mi < 2; mi++)
    #pragma unroll
    for (int ni = 0; ni < 2; ni++)
      acc[mi][ni] = (f32x4){0.f,0.f,0.f,0.f};
  #pragma unroll
  for (int kc = 0; kc < K/32; kc++) {
    f16x8 a[2], b[2];
    #pragma unroll
    for (int mi = 0; mi < 2; mi++)
      a[mi] = *(const f16x8*)(sA + (wm*32 + mi*16 + l15)*LK + kc*32 + g*8);
    #pragma unroll
    for (int ni = 0; ni < 2; ni++)
      b[ni] = *(const f16x8*)(sB + (wn*32 + ni*16 + l15)*LK + kc*32 + g*8);
    #pragma unroll
    for (int mi = 0; mi < 2; mi++)
      #pragma unroll
      for (int ni = 0; ni < 2; ni++)
        acc[mi][ni] = __builtin_amdgcn_mfma_f32_16x16x32_f16(a[mi], b[ni], acc[mi][ni], 0, 0, 0);
  }
  #pragma unroll
  for (int mi = 0; mi < 2; mi++)
    #pragma unroll
    for (int ni = 0; ni < 2; ni++)
      #pragma unroll
      for (int j = 0; j < 4; j++) {
        int m = m0 + wm*32 + mi*16 + g*4 + j;
        int n = n0 + wn*32 + ni*16 + l15;
        if (m < M) C[(size_t)m*N + n] = acc[mi][ni][j];
      }
}

// ==================== ARMA combine kernels ====================
// C layout per row: [t_k0(128) | t_k1(128) | root_k0(128) | root_k1(128)]
__global__ __launch_bounds__(256) void combine128(
    const float* __restrict__ C, const int* __restrict__ ip,
    const int* __restrict__ csrs, const float* __restrict__ csrn,
    const float* __restrict__ bias, f16* __restrict__ hout)
{
  const int d = blockIdx.x*4 + (threadIdx.x >> 6);
  const int lane = threadIdx.x & 63;
  const int i0 = ip[d], i1 = ip[d+1];
  float a00 = 0.f, a01 = 0.f, a10 = 0.f, a11 = 0.f;
  float b00 = 0.f, b01 = 0.f, b10 = 0.f, b11 = 0.f;
  int e = i0;
  for (; e + 1 < i1; e += 2) {                    // 2-edge unroll: 8 independent streams
    int s0 = csrs[e], s1 = csrs[e+1];
    float w0 = csrn[e], w1 = csrn[e+1];
    const float* t0 = C + (size_t)s0*512;
    const float* t1 = C + (size_t)s1*512;
    a00 += w0*t0[lane];       a01 += w0*t0[lane+64];
    a10 += w0*t0[lane+128];   a11 += w0*t0[lane+192];
    b00 += w1*t1[lane];       b01 += w1*t1[lane+64];
    b10 += w1*t1[lane+128];   b11 += w1*t1[lane+192];
  }
  if (e < i1) {
    int s = csrs[e];
    float w = csrn[e];
    const float* t = C + (size_t)s*512;
    a00 += w*t[lane];       a01 += w*t[lane+64];
    a10 += w*t[lane+128];   a11 += w*t[lane+192];
  }
  a00 += b00; a01 += b01; a10 += b10; a11 += b11;
  const float* r = C + (size_t)d*512 + 256;
  float o0 = fmaxf(a00 + r[lane]     + bias[lane],     0.f)
           + fmaxf(a10 + r[lane+128] + bias[lane+128], 0.f);
  float o1 = fmaxf(a01 + r[lane+64]  + bias[lane+64],  0.f)
           + fmaxf(a11 + r[lane+192] + bias[lane+192], 0.f);
  hout[(size_t)d*128 + lane]      = (f16)tanhf(0.5f*o0);
  hout[(size_t)d*128 + lane + 64] = (f16)tanhf(0.5f*o1);
}

// layer 6 (K=1, Fout=16): C row = [t(16) | root(16) | zeros(32)]; relu -> softmax -> out
__global__ __launch_bounds__(256) void combine_out(
    const float* __restrict__ C, const int* __restrict__ ip,
    const int* __restrict__ csrs, const float* __restrict__ csrn,
    const float* __restrict__ bias, float* __restrict__ out)
{
  const int d = blockIdx.x*4 + (threadIdx.x >> 6);
  const int lane = threadIdx.x & 63;
  const int f = lane & 15;
  const int i0 = ip[d], i1 = ip[d+1];
  float a = 0.f, b = 0.f;
  int e = i0;
  for (; e + 1 < i1; e += 2) {
    a += csrn[e]   * C[(size_t)csrs[e]*64 + f];
    b += csrn[e+1] * C[(size_t)csrs[e+1]*64 + f];
  }
  if (e < i1) a += csrn[e] * C[(size_t)csrs[e]*64 + f];
  a += b;
  float v = fmaxf(a + C[(size_t)d*64 + 16 + f] + bias[f], 0.f);
  float m = v;
  #pragma unroll
  for (int off = 1; off < 16; off <<= 1) m = fmaxf(m, __shfl_xor(m, off));
  float ev = expf(v - m);
  float s = ev;
  #pragma unroll
  for (int off = 1; off < 16; off <<= 1) s += __shfl_xor(s, off);
  if (lane < 16) out[(size_t)d*16 + lane] = ev / s;
}

// ==================== host ====================
extern "C" void kernel_launch(void* const* d_in, const int* in_sizes, int n_in,
                              void* d_out, int out_size, void* d_ws, size_t ws_size,
                              hipStream_t stream)
{
  const float* inputs = (const float*)d_in[0];
  const int*   ei     = (const int*)d_in[1];
  const float* e1w = (const float*)d_in[2];
  const float* e1b = (const float*)d_in[3];
  const float* e2w = (const float*)d_in[4];
  const float* e2b = (const float*)d_in[5];
  const float* e3w = (const float*)d_in[6];
  const float* e3b = (const float*)d_in[7];
  const float *awi[6], *awr[6], *ab[6];
  for (int i = 0; i < 6; i++) {
    awi[i] = (const float*)d_in[8 + 3*i];
    awr[i] = (const float*)d_in[9 + 3*i];
    ab[i]  = (const float*)d_in[10 + 3*i];
  }
  char* ws = (char*)d_ws;
  f16* W2T = (f16*)(ws + OFF_W2T);
  f16* W3T = (f16*)(ws + OFF_W3T);
  f16* W1T = (f16*)(ws + OFF_W1T);
  f16* WT[6] = { (f16*)(ws + OFF_WT1), (f16*)(ws + OFF_WT2), (f16*)(ws + OFF_WT3),
                 (f16*)(ws + OFF_WT4), (f16*)(ws + OFF_WT5), (f16*)(ws + OFF_WT6) };
  f16* H0 = (f16*)(ws + OFF_H0);
  f16* HA = (f16*)(ws + OFF_HA);
  f16* HB = (f16*)(ws + OFF_HB);
  float* C = (float*)(ws + OFF_C);
  int* DEG = (int*)(ws + OFF_DEG);
  int* IP  = (int*)(ws + OFF_IP);
  int* CUR = (int*)(ws + OFF_CUR);
  float* DINV = (float*)(ws + OFF_DINV);
  int* CSRS = (int*)(ws + OFF_CSRS);
  float* CSRN = (float*)(ws + OFF_CSRN);

  (void)hipFuncSetAttribute((const void*)cnn_kernel,
                            hipFuncAttributeMaxDynamicSharedMemorySize, LDS_TOTAL);

  // weight prep (W1T aliases C; cnn reads it before first gemm writes C)
  prep_w2t<<<672, 256, 0, stream>>>(e2w, W2T);
  prep_w3t<<<5, 256, 0, stream>>>(e3w, W3T);
  prep_w1t<<<14, 256, 0, stream>>>(e1w, W1T);
  prep_wt<<<192, 256, 0, stream>>>(awi[0], awr[0], WT[0], 2, 94, 128, 96, 512);
  for (int l = 1; l < 5; l++)
    prep_wt<<<256, 256, 0, stream>>>(awi[l], awr[l], WT[l], 2, 128, 128, 128, 512);
  prep_wt<<<32, 256, 0, stream>>>(awi[5], awr[5], WT[5], 1, 128, 16, 128, 64);

  // graph norm + CSR by dst
  zero_kernel<<<20, 256, 0, stream>>>(DEG, CUR);
  deg_kernel<<<625, 256, 0, stream>>>(ei, DEG);
  scan_kernel<<<1, 1024, 0, stream>>>(DEG, IP, DINV);
  csr_fill<<<625, 256, 0, stream>>>(ei, DINV, IP, CUR, CSRS, CSRN);

  // fused CNN encoder -> h0 f16 [5000][96]
  cnn_kernel<<<NN, 512, LDS_TOTAL, stream>>>(inputs, W1T, e1b, W2T, e2b, W3T, e3b, H0);

  // ARMA stack
  gemm_kernel<96><<<dim3(79, 8), 256, 0, stream>>>(H0, WT[0], C, NN, 512);
  combine128<<<1250, 256, 0, stream>>>(C, IP, CSRS, CSRN, ab[0], HA);
  gemm_kernel<128><<<dim3(79, 8), 256, 0, stream>>>(HA, WT[1], C, NN, 512);
  combine128<<<1250, 256, 0, stream>>>(C, IP, CSRS, CSRN, ab[1], HB);
  gemm_kernel<128><<<dim3(79, 8), 256, 0, stream>>>(HB, WT[2], C, NN, 512);
  combine128<<<1250, 256, 0, stream>>>(C, IP, CSRS, CSRN, ab[2], HA);
  gemm_kernel<128><<<dim3(79, 8), 256, 0, stream>>>(HA, WT[3], C, NN, 512);
  combine128<<<1250, 256, 0, stream>>>(C, IP, CSRS, CSRN, ab[3], HB);
  gemm_kernel<128><<<dim3(79, 8), 256, 0, stream>>>(HB, WT[4], C, NN, 512);
  combine128<<<1250, 256, 0, stream>>>(C, IP, CSRS, CSRN, ab[4], HA);
  gemm_kernel<128><<<dim3(79, 1), 256, 0, stream>>>(HA, WT[5], C, NN, 64);
  combine_out<<<1250, 256, 0, stream>>>(C, IP, CSRS, CSRN, ab[5], (float*)d_out);
}